// Round 12
// baseline (21.781 us; speedup 1.0000x reference)
//
#include <hip/hip_runtime.h>

#define DD 128   // feature dim, fixed by the reference

typedef float v2f __attribute__((ext_vector_type(2)));
typedef float v4f __attribute__((ext_vector_type(4)));
typedef float v8f __attribute__((ext_vector_type(8)));

// Packed per-pair update: z = x*a + c; zz = z*z; p *= (1 - zz); s += zz.
#define UPD2(P, S, XX, AA, CC)                                   \
    {                                                            \
        v2f z  = __builtin_elementwise_fma((XX), (AA), (CC));    \
        v2f zz = z * z;                                          \
        P = __builtin_elementwise_fma(-zz, P, P);                \
        S += zz;                                                 \
    }

// One row's update for a quad-pair (8 d) against a0/c0, a1/c1.
#define UPD8(P, S, XV)                                           \
    {                                                            \
        UPD2(P, S, (XV).lo.lo, a0.lo, c0.lo);                    \
        UPD2(P, S, (XV).lo.hi, a0.hi, c0.hi);                    \
        UPD2(P, S, (XV).hi.lo, a1.lo, c1.lo);                    \
        UPD2(P, S, (XV).hi.hi, a1.hi, c1.hi);                    \
    }

// Tile: 32 n x 64 b per block, 512 threads (8 waves), grid 512 = 2 blocks/CU
//   -> 4 waves/SIMD (2x R11) so the LDS pipe overlaps the VALU pipe instead
//   of serializing (R5/R6 showed the pipes additive at low occupancy).
// lane = (half<<5) | ncol: ncol = n-column (32), half picks 4 of the wave's
//   8 b-rows. Lanes l and l+32 read the SAME a/c address -> LDS broadcast
//   (free, m136); unique bytes/read halve, offsetting the 2x wave count.
// LDS: a = 1/scale, c = -bias/scale as [32 rows][32 quads] v4f (32 KB),
//   quad slot XOR-swizzled by (row&7); read arow[q ^ (ncol&7)] = quad q of
//   row ncol (slot q^s holds quad (q^s)^s = q -- pairing verified).
// x: 2-way-divergent VMEM v8f loads (coalesced 32 B segments, L2-resident),
//   decoupled from the lgkmcnt domain. Fold-32 numerics identical to R11.
// ~70 live regs (4 rows), no arrays, no manual prefetch (R7/R8 spill lesson).
__global__ __launch_bounds__(512, 4)
void wavelet_prod_kernel(const float* __restrict__ x,
                         const float* __restrict__ bias,
                         const float* __restrict__ scale,
                         float* __restrict__ out,
                         int B, int N)
{
    __shared__ v4f a_s[32 * 32];
    __shared__ v4f c_s[32 * 32];

    const int tid  = threadIdx.x;
    const int lane = tid & 63;
    const int wave = tid >> 6;
    const int ncol = lane & 31;
    const int half = lane >> 5;

    const int n0 = blockIdx.x * 32;   // 32 n per block (one per lane-column)
    const int bb = blockIdx.y * 64;   // 64 b per block (8 per wave, 4 per thread)

    // ---- one-time staging: 32 x 128 bias/scale tile -> a,c in LDS ----
    {
        const v4f* b4 = (const v4f*)(bias  + (size_t)n0 * DD);
        const v4f* s4 = (const v4f*)(scale + (size_t)n0 * DD);
        #pragma unroll
        for (int k = 0; k < 2; ++k) {
            int flat = tid + k * 512;          // 0..1023 v4f slots
            int r = flat >> 5;                 // n-row within tile (0..31)
            int q = flat & 31;                 // d-quad (0..31)
            v4f sv = s4[flat];
            v4f bv = b4[flat];
            v4f av, cv;
            av.x = __builtin_amdgcn_rcpf(sv.x);
            av.y = __builtin_amdgcn_rcpf(sv.y);
            av.z = __builtin_amdgcn_rcpf(sv.z);
            av.w = __builtin_amdgcn_rcpf(sv.w);
            cv = -bv * av;
            int dst = r * 32 + (q ^ (r & 7));
            a_s[dst] = av;
            c_s[dst] = cv;
        }
    }
    __syncthreads();

    const int r0 = bb + wave * 8 + half * 4;             // thread's 4 b-rows
    const v8f* xr8 = (const v8f*)(x + (size_t)r0 * DD);  // rows stride 16 v8f

    const v4f* arow = a_s + ncol * 32;
    const v4f* crow = c_s + ncol * 32;
    const int sw = ncol & 7;

    // Two packed chains per row, merged at each 32-d fold (16 factors/chain).
    v2f p0 = {1.f, 1.f}, p1 = {1.f, 1.f}, p2 = {1.f, 1.f}, p3 = {1.f, 1.f};
    v2f s0 = {0.f, 0.f}, s1 = {0.f, 0.f}, s2 = {0.f, 0.f}, s3 = {0.f, 0.f};

    const float kexp = -0.7213475204444817f;  // -0.5 * log2(e)

    #pragma unroll
    for (int w = 0; w < 4; ++w) {             // 4 folds of 32 d
        #pragma unroll
        for (int h = 0; h < 4; ++h) {         // 4 quad-pairs per fold window
            const int q0 = w * 8 + h * 2;     // quads q0, q0+1
            const int sl0 = q0 ^ sw;
            const int sl1 = (q0 + 1) ^ sw;
            v4f a0 = arow[sl0], c0 = crow[sl0];
            v4f a1 = arow[sl1], c1 = crow[sl1];
            const int xi = w * 4 + h;         // v8f index within row
            v8f x0 = xr8[0 * 16 + xi];
            v8f x1 = xr8[1 * 16 + xi];
            v8f x2 = xr8[2 * 16 + xi];
            v8f x3 = xr8[3 * 16 + xi];
            UPD8(p0, s0, x0);
            UPD8(p1, s1, x1);
            UPD8(p2, s2, x2);
            UPD8(p3, s3, x3);
        }
        // fold Gaussian factor + merge packed chains every 32 d
        p0.x = p0.x * p0.y * __builtin_amdgcn_exp2f((s0.x + s0.y) * kexp);
        p0.y = 1.f; s0 = (v2f){0.f, 0.f};
        p1.x = p1.x * p1.y * __builtin_amdgcn_exp2f((s1.x + s1.y) * kexp);
        p1.y = 1.f; s1 = (v2f){0.f, 0.f};
        p2.x = p2.x * p2.y * __builtin_amdgcn_exp2f((s2.x + s2.y) * kexp);
        p2.y = 1.f; s2 = (v2f){0.f, 0.f};
        p3.x = p3.x * p3.y * __builtin_amdgcn_exp2f((s3.x + s3.y) * kexp);
        p3.y = 1.f; s3 = (v2f){0.f, 0.f};
    }

    float* o = out + (size_t)r0 * N + n0 + ncol;
    o[0 * N] = p0.x;
    o[1 * N] = p1.x;
    o[2 * N] = p2.x;
    o[3 * N] = p3.x;
}

extern "C" void kernel_launch(void* const* d_in, const int* in_sizes, int n_in,
                              void* d_out, int out_size, void* d_ws, size_t ws_size,
                              hipStream_t stream)
{
    const float* x     = (const float*)d_in[0];
    const float* bias  = (const float*)d_in[1];
    const float* scale = (const float*)d_in[2];
    float* out = (float*)d_out;

    const int B = in_sizes[0] / DD;   // 2048
    const int N = in_sizes[1] / DD;   // 512

    dim3 grid(N / 32, B / 64);        // (16, 32) = 512 blocks = 2 per CU
    wavelet_prod_kernel<<<grid, 512, 0, stream>>>(x, bias, scale, out, B, N);
}